// Round 3
// baseline (150.943 us; speedup 1.0000x reference)
//
#include <hip/hip_runtime.h>
#include <math.h>

#define B_SZ 1024
#define E_SZ 512
#define C_SZ 16384
#define MRG 0.1f
#define ALPHA 32.0f
#define A2LOG2E 46.16624090918536f   /* ALPHA * log2(e) */
#define K_HY 1.0f
#define LAM 0.1f

typedef __bf16 bf16;
typedef bf16 bf16x8 __attribute__((ext_vector_type(8)));
typedef float f32x4 __attribute__((ext_vector_type(4)));

__device__ __forceinline__ void async16(const void* g, void* l) {
    __builtin_amdgcn_global_load_lds(
        (const __attribute__((address_space(1))) void*)g,
        (__attribute__((address_space(3))) void*)l,
        16, 0, 0);
}

// ---------------- fused prep: proxy_norm | convert_inputs | class_scalars | count_targets
// Block-range dispatch; all four roles are independent and precede the GEMM.
//   [0,4096)    proxy row-l2norm -> bf16 (one wave per row, 4 rows/block)
//   [4096,4352) inputs f32 -> bf16
//   [4352,4416) per-class scalars oSim/iEff
//   [4416,4420) target counts
__global__ __launch_bounds__(256) void prep_fused(
    const float* __restrict__ proxies, bf16* __restrict__ Pbf,
    const float* __restrict__ inputs, bf16* __restrict__ Abf,
    const float* __restrict__ effNum, const float* __restrict__ lSim,
    float* __restrict__ oSim, float* __restrict__ iEff,
    const int* __restrict__ tg, int* __restrict__ cnt) {
    const int blk = blockIdx.x;
    const int tid = threadIdx.x;
    if (blk < 4096) {
        int row = blk * 4 + (tid >> 6);
        int lane = tid & 63;
        const float* pr = proxies + (size_t)row * E_SZ + lane * 8;
        float4 v0 = *(const float4*)pr;
        float4 v1 = *(const float4*)(pr + 4);
        float ss = v0.x * v0.x + v0.y * v0.y + v0.z * v0.z + v0.w * v0.w +
                   v1.x * v1.x + v1.y * v1.y + v1.z * v1.z + v1.w * v1.w;
#pragma unroll
        for (int m = 1; m < 64; m <<= 1) ss += __shfl_xor(ss, m);
        float inv = 1.0f / sqrtf(ss + 1e-12f);
        bf16x8 o;
        o[0] = (bf16)(v0.x * inv); o[1] = (bf16)(v0.y * inv);
        o[2] = (bf16)(v0.z * inv); o[3] = (bf16)(v0.w * inv);
        o[4] = (bf16)(v1.x * inv); o[5] = (bf16)(v1.y * inv);
        o[6] = (bf16)(v1.z * inv); o[7] = (bf16)(v1.w * inv);
        *(bf16x8*)(Pbf + (size_t)row * E_SZ + lane * 8) = o;
    } else if (blk < 4352) {
        int i = ((blk - 4096) * 256 + tid) * 8;
        float4 v0 = *(const float4*)(inputs + i);
        float4 v1 = *(const float4*)(inputs + i + 4);
        bf16x8 o;
        o[0] = (bf16)v0.x; o[1] = (bf16)v0.y; o[2] = (bf16)v0.z; o[3] = (bf16)v0.w;
        o[4] = (bf16)v1.x; o[5] = (bf16)v1.y; o[6] = (bf16)v1.z; o[7] = (bf16)v1.w;
        *(bf16x8*)(Abf + i) = o;
    } else if (blk < 4416) {
        int c = (blk - 4352) * 256 + tid;     // exactly covers [0, C_SZ)
        float en = effNum[c], ls = lSim[c];
        float wb = 1.0f / (1.0f + log1pf(en));
        float eta = (1.0f + K_HY * (1.0f - ls)) * wb + LAM;
        oSim[c] = ls - eta;
        iEff[c] = 1.0f / fmaxf(1.0f, en);
    } else {
        int i = (blk - 4416) * 256 + tid;     // exactly covers [0, B_SZ)
        atomicAdd(&cnt[tg[i]], 1);
    }
}

// ---------------- fused GEMM (bf16 MFMA) + epilogue ----------------
// Tile: BM=128 (batch rows), BN=128 (classes), BK=32. 4 waves, each 64x64.
// Double-buffered LDS with counted vmcnt (T3/T4 minimum-2-phase): the 4
// prefetch loads stay in flight across BOTH barriers; vmcnt(4) waits only
// on the 4 tile-t loads issued one phase earlier (FIFO retirement).
// Fragment reads XOR-swizzled (slot ^= g(row&15), g(r)=(r^(r>>2))&3) with
// the inverse permutation applied on the GLOBAL source, keeping
// global_load_lds's linear LDS destination (rule #21 both-sides).
// Audit notes: barrier count is wave-uniform (full unroll); epilogue LDS
// scratch lives in Alds[0], last read strictly before t=15's BARRIER_A.
__global__ __launch_bounds__(256) void gemm_epilogue(
    const bf16* __restrict__ Abf,   // [B][E]
    const bf16* __restrict__ Pbf,   // [C][E] normalized
    const int* __restrict__ targets,
    const float* __restrict__ oSimA,
    const float* __restrict__ iEffA,
    float* __restrict__ posExp,
    float* __restrict__ negExp,
    float* __restrict__ negVals) {
    __shared__ __align__(16) bf16 Alds[2][128 * 32];
    __shared__ __align__(16) bf16 Blds[2][128 * 32];
    __shared__ int tgtLds[128];

    const int tid = threadIdx.x;
    const int wave = tid >> 6, lane = tid & 63;
    const int quad = lane >> 4, l16 = lane & 15;
    const int wRow = (wave >> 1) * 64, wCol = (wave & 1) * 64;
    const int bn0 = blockIdx.x * 128, bm0 = blockIdx.y * 128;

    if (tid < 128) tgtLds[tid] = targets[bm0 + tid];

    f32x4 zero = {0.f, 0.f, 0.f, 0.f};
    f32x4 acc[4][4];
#pragma unroll
    for (int i = 0; i < 4; ++i)
#pragma unroll
        for (int j = 0; j < 4; ++j) acc[i][j] = zero;

    // ---- staging addresses (pre-swizzled global source, linear LDS dest) ----
    const int ldRow = lane >> 2;                       // row within 16-row chunk
    const int swzS = (ldRow ^ (ldRow >> 2)) & 3;       // slot swizzle for this row
    const int ldK = ((lane & 3) ^ swzS) * 8;           // bf16 col offset (swizzled)

    const bf16* gA = Abf + (size_t)(bm0 + wave * 32 + ldRow) * E_SZ + ldK;
    const bf16* gB = Pbf + (size_t)(bn0 + wave * 32 + ldRow) * E_SZ + ldK;

    // ---- fragment read offsets (same XOR on the read side) ----
    const int rswz = (l16 ^ (l16 >> 2)) & 3;
    int aOff[4], bOff[4];
#pragma unroll
    for (int mi = 0; mi < 4; ++mi)
        aOff[mi] = (wRow + mi * 16 + l16) * 32 + ((quad ^ rswz) * 8);
#pragma unroll
    for (int ni = 0; ni < 4; ++ni)
        bOff[ni] = (wCol + ni * 16 + l16) * 32 + ((quad ^ rswz) * 8);

    __syncthreads();   // full drain: vmcnt==0 for every wave entering the loop

    // prologue: stage tile 0 into buffer 0
#pragma unroll
    for (int j = 0; j < 2; ++j) {
        int chunk = wave * 2 + j;
        async16(gA + (size_t)j * 16 * E_SZ, &Alds[0][chunk * 512]);
        async16(gB + (size_t)j * 16 * E_SZ, &Blds[0][chunk * 512]);
    }

#pragma unroll
    for (int t = 0; t < 16; ++t) {
        const int cur = t & 1;
        // BARRIER_A: everyone finished reading buf[1-cur] (iteration t-1)
        __builtin_amdgcn_s_barrier();
        __builtin_amdgcn_sched_barrier(0);
        if (t < 15) {
            const int k0 = (t + 1) * 32;
#pragma unroll
            for (int j = 0; j < 2; ++j) {
                int chunk = wave * 2 + j;
                async16(gA + (size_t)j * 16 * E_SZ + k0, &Alds[1 - cur][chunk * 512]);
                async16(gB + (size_t)j * 16 * E_SZ + k0, &Blds[1 - cur][chunk * 512]);
            }
            // my 4 tile-t loads (issued last iter) done; 4 prefetch stay in flight
            asm volatile("s_waitcnt vmcnt(4)" ::: "memory");
        } else {
            asm volatile("s_waitcnt vmcnt(0)" ::: "memory");
        }
        // BARRIER_B: all waves' tile-t loads have landed in buf[cur]
        __builtin_amdgcn_s_barrier();
        __builtin_amdgcn_sched_barrier(0);

        bf16x8 af[4], bff[4];
#pragma unroll
        for (int mi = 0; mi < 4; ++mi)
            af[mi] = *(const bf16x8*)&Alds[cur][aOff[mi]];
#pragma unroll
        for (int ni = 0; ni < 4; ++ni)
            bff[ni] = *(const bf16x8*)&Blds[cur][bOff[ni]];
#pragma unroll
        for (int mi = 0; mi < 4; ++mi)
#pragma unroll
            for (int ni = 0; ni < 4; ++ni)
                acc[mi][ni] = __builtin_amdgcn_mfma_f32_16x16x32_bf16(
                    af[mi], bff[ni], acc[mi][ni], 0, 0, 0);
    }
    __builtin_amdgcn_sched_barrier(0);  // keep epilogue loads out of the K-loop

    // -------- epilogue: per-class (column) reductions --------
    int colG[4];
    float oS[4], iE[4];
#pragma unroll
    for (int ni = 0; ni < 4; ++ni) {
        colG[ni] = bn0 + wCol + ni * 16 + l16;
        oS[ni] = oSimA[colG[ni]];
        iE[ni] = iEffA[colG[ni]];
    }
    float negE[4] = {0.f, 0.f, 0.f, 0.f};
    float negV[4] = {0.f, 0.f, 0.f, 0.f};
#pragma unroll
    for (int mi = 0; mi < 4; ++mi) {
#pragma unroll
        for (int r = 0; r < 4; ++r) {
            int rowL = wRow + mi * 16 + quad * 4 + r;
            int tgt = tgtLds[rowL];
#pragma unroll
            for (int ni = 0; ni < 4; ++ni) {
                float cosv = acc[mi][ni][r];
                if (tgt == colG[ni]) {
                    // positive position: mask = 1 (rare: ~1 hit per block)
                    atomicAdd(&posExp[colG[ni]],
                              __builtin_amdgcn_exp2f(A2LOG2E * (MRG - cosv)));
                } else {
                    float nv = (cosv < oS[ni]) ? iE[ni] : 1.0f;
                    negE[ni] += __builtin_amdgcn_exp2f(A2LOG2E * (cosv + MRG) * nv);
                    negV[ni] += nv;
                }
            }
        }
    }
    // quad-level register reduce: quad==0 lane holds the 64-row partial
#pragma unroll
    for (int ni = 0; ni < 4; ++ni) {
        negE[ni] += __shfl_xor(negE[ni], 16); negE[ni] += __shfl_xor(negE[ni], 32);
        negV[ni] += __shfl_xor(negV[ni], 16); negV[ni] += __shfl_xor(negV[ni], 32);
    }
    // LDS combine across the two waves sharing each column half, then one
    // coalesced global atomic per column. Scratch is Alds[0][0..255] floats —
    // disjoint from Alds[1]/Blds[1] (the t=15 buffers); Alds[0]'s last read
    // (t=14 MFMA phase) precedes t=15's BARRIER_A, so no extra barrier needed.
    float* nEsh = (float*)&Alds[0][0];     // 128 floats
    float* nVsh = nEsh + 128;              // 128 floats
    nEsh[tid & 255] = 0.0f;                // 256 threads zero 256 floats
    __syncthreads();
    if (quad == 0) {
#pragma unroll
        for (int ni = 0; ni < 4; ++ni) {
            int cl = wCol + ni * 16 + l16;
            atomicAdd(&nEsh[cl], negE[ni]);
            atomicAdd(&nVsh[cl], negV[ni]);
        }
    }
    __syncthreads();
    if (tid < 128) {
        atomicAdd(&negExp[bn0 + tid], nEsh[tid]);
        atomicAdd(&negVals[bn0 + tid], nVsh[tid]);
    }
}

// ---------------- finalize: single block, grid-stride + two-level reduce ----------------
__global__ __launch_bounds__(1024) void finalize(
    const float* __restrict__ posExp, const float* __restrict__ negExp,
    const float* __restrict__ negVals, const int* __restrict__ cCnt,
    float* __restrict__ out) {
    const int tid = threadIdx.x;
    float pt = 0.f, nt = 0.f, pws = 0.f, nws = 0.f;
    for (int c = tid; c < C_SZ; c += 1024) {
        pt += log1pf(posExp[c]);
        nt += log1pf(negExp[c]);
        int cnt = cCnt[c];
        pws += (cnt > 0) ? 1.0f : 0.0f;
        int Nc = B_SZ - cnt;
        nws += (Nc > 0) ? negVals[c] / (float)Nc : 0.0f;
    }
#pragma unroll
    for (int m = 1; m < 64; m <<= 1) {
        pt += __shfl_xor(pt, m);
        nt += __shfl_xor(nt, m);
        pws += __shfl_xor(pws, m);
        nws += __shfl_xor(nws, m);
    }
    __shared__ float red[16][4];
    int wv = tid >> 6;
    if ((tid & 63) == 0) {
        red[wv][0] = pt; red[wv][1] = nt; red[wv][2] = pws; red[wv][3] = nws;
    }
    __syncthreads();
    if (tid < 16) {
        float a = red[tid][0], b = red[tid][1], c2 = red[tid][2], d = red[tid][3];
#pragma unroll
        for (int m = 1; m < 16; m <<= 1) {
            a += __shfl_xor(a, m); b += __shfl_xor(b, m);
            c2 += __shfl_xor(c2, m); d += __shfl_xor(d, m);
        }
        if (tid == 0) out[0] = a / c2 + b / d;
    }
}

extern "C" void kernel_launch(void* const* d_in, const int* in_sizes, int n_in,
                              void* d_out, int out_size, void* d_ws, size_t ws_size,
                              hipStream_t stream) {
    const float* inputs = (const float*)d_in[0];
    const int* targets = (const int*)d_in[1];
    const float* proxies = (const float*)d_in[2];
    const float* effNum = (const float*)d_in[3];
    const float* lSim = (const float*)d_in[4];
    float* out = (float*)d_out;

    // workspace layout
    bf16* Pbf = (bf16*)d_ws;                        // C*E bf16  (16 MB)
    bf16* Abf = Pbf + (size_t)C_SZ * E_SZ;          // B*E bf16  (1 MB)
    float* oSim = (float*)(Abf + (size_t)B_SZ * E_SZ);
    float* iEff = oSim + C_SZ;
    float* posExp = iEff + C_SZ;
    float* negExp = posExp + C_SZ;
    float* negVals = negExp + C_SZ;
    int* cCnt = (int*)(negVals + C_SZ);

    // zero the accumulator arrays (posExp, negExp, negVals, cCnt contiguous)
    hipMemsetAsync(posExp, 0, (size_t)4 * C_SZ * sizeof(float), stream);

    prep_fused<<<4420, 256, 0, stream>>>(proxies, Pbf, inputs, Abf,
                                         effNum, lSim, oSim, iEff, targets, cCnt);
    gemm_epilogue<<<dim3(C_SZ / 128, B_SZ / 128), 256, 0, stream>>>(
        Abf, Pbf, targets, oSim, iEff, posExp, negExp, negVals);
    finalize<<<1, 1024, 0, stream>>>(posExp, negExp, negVals, cCnt, out);
}

// Round 4
// 116.901 us; speedup vs baseline: 1.2912x; 1.2912x over previous
//
#include <hip/hip_runtime.h>
#include <math.h>

#define B_SZ 1024
#define E_SZ 512
#define C_SZ 16384
#define MRG 0.1f
#define ALPHA 32.0f
#define A2LOG2E 46.16624090918536f   /* ALPHA * log2(e) */
#define K_HY 1.0f
#define LAM 0.1f

#define BM 256
#define BN 256
#define BK 64          /* bf16 elements = 128 B */

typedef __bf16 bf16;
typedef bf16 bf16x8 __attribute__((ext_vector_type(8)));
typedef float f32x4 __attribute__((ext_vector_type(4)));

__device__ __forceinline__ void async16(const void* g, void* l) {
    __builtin_amdgcn_global_load_lds(
        (const __attribute__((address_space(1))) void*)g,
        (__attribute__((address_space(3))) void*)l,
        16, 0, 0);
}

// ---------------- fused prep: proxy_norm | convert_inputs | class_scalars | zero-accum
//   [0,4096)     proxy row-l2norm -> bf16 (one wave per row, 4 rows/block)
//   [4096,4352)  inputs f32 -> bf16
//   [4352,4416)  per-class scalars oSim/iEff
//   [4416,4481)  zero posExp/negExp/negVals/cCnt/acc4/counter (65541 floats + pad)
__global__ __launch_bounds__(256) void prep_fused(
    const float* __restrict__ proxies, bf16* __restrict__ Pbf,
    const float* __restrict__ inputs, bf16* __restrict__ Abf,
    const float* __restrict__ effNum, const float* __restrict__ lSim,
    float* __restrict__ oSim, float* __restrict__ iEff,
    float* __restrict__ zeroBase) {
    const int blk = blockIdx.x;
    const int tid = threadIdx.x;
    if (blk < 4096) {
        int row = blk * 4 + (tid >> 6);
        int lane = tid & 63;
        const float* pr = proxies + (size_t)row * E_SZ + lane * 8;
        float4 v0 = *(const float4*)pr;
        float4 v1 = *(const float4*)(pr + 4);
        float ss = v0.x * v0.x + v0.y * v0.y + v0.z * v0.z + v0.w * v0.w +
                   v1.x * v1.x + v1.y * v1.y + v1.z * v1.z + v1.w * v1.w;
#pragma unroll
        for (int m = 1; m < 64; m <<= 1) ss += __shfl_xor(ss, m);
        float inv = 1.0f / sqrtf(ss + 1e-12f);
        bf16x8 o;
        o[0] = (bf16)(v0.x * inv); o[1] = (bf16)(v0.y * inv);
        o[2] = (bf16)(v0.z * inv); o[3] = (bf16)(v0.w * inv);
        o[4] = (bf16)(v1.x * inv); o[5] = (bf16)(v1.y * inv);
        o[6] = (bf16)(v1.z * inv); o[7] = (bf16)(v1.w * inv);
        *(bf16x8*)(Pbf + (size_t)row * E_SZ + lane * 8) = o;
    } else if (blk < 4352) {
        int i = ((blk - 4096) * 256 + tid) * 8;
        float4 v0 = *(const float4*)(inputs + i);
        float4 v1 = *(const float4*)(inputs + i + 4);
        bf16x8 o;
        o[0] = (bf16)v0.x; o[1] = (bf16)v0.y; o[2] = (bf16)v0.z; o[3] = (bf16)v0.w;
        o[4] = (bf16)v1.x; o[5] = (bf16)v1.y; o[6] = (bf16)v1.z; o[7] = (bf16)v1.w;
        *(bf16x8*)(Abf + i) = o;
    } else if (blk < 4416) {
        int c = (blk - 4352) * 256 + tid;     // exactly covers [0, C_SZ)
        float en = effNum[c], ls = lSim[c];
        float wb = 1.0f / (1.0f + log1pf(en));
        float eta = (1.0f + K_HY * (1.0f - ls)) * wb + LAM;
        oSim[c] = ls - eta;
        iEff[c] = 1.0f / fmaxf(1.0f, en);
    } else {
        // zero 4*C_SZ + 8 floats (posExp,negExp,negVals,cCnt,acc4,counter,pad)
        int i = (blk - 4416) * 256 + tid;
        if (i < 16386) {
            float4 z = {0.f, 0.f, 0.f, 0.f};
            *(float4*)(zeroBase + (size_t)i * 4) = z;
        }
    }
}

// ---------------- fused GEMM (bf16 MFMA) + epilogue ----------------
// Tile: BM=256 x BN=256 x BK=64, 8 waves (2M x 4N), per-wave output 128x64.
// Grid 64x4 = 256 blocks = 1/CU (128KB LDS). Double-buffered, counted
// vmcnt(8) 2-phase (verified skeleton from the 128^2 kernel, re-parameterized).
// LDS swizzle: 16B-slot s of row r holds global slot s^(r&7); staging applies
// the inverse on the GLOBAL source (linear LDS dest for global_load_lds),
// reads apply the same XOR (rule #21 both-sides). Full-wave ds_read_b128 is
// then exactly uniform: 8 lanes per 4-bank group (the b128 floor).
__global__ __launch_bounds__(512, 2) void gemm_epilogue(
    const bf16* __restrict__ Abf,   // [B][E]
    const bf16* __restrict__ Pbf,   // [C][E] normalized
    const int* __restrict__ targets,
    const float* __restrict__ oSimA,
    const float* __restrict__ iEffA,
    float* __restrict__ posExp,
    float* __restrict__ negExp,
    float* __restrict__ negVals,
    int* __restrict__ cCnt) {
    __shared__ __align__(16) bf16 Alds[2][BM * BK];   // 2 x 32 KB
    __shared__ __align__(16) bf16 Blds[2][BN * BK];   // 2 x 32 KB
    __shared__ int tgtLds[BM];
    __shared__ float scratch[2 * BN];                 // epilogue combine

    const int tid = threadIdx.x;
    const int wave = tid >> 6, lane = tid & 63;
    const int quad = lane >> 4, l16 = lane & 15;
    const int wm = wave >> 2, wn = wave & 3;          // 2M x 4N wave grid
    const int bn0 = blockIdx.x * BN, bm0 = blockIdx.y * BM;

    if (tid < BM) tgtLds[tid] = targets[bm0 + tid];

    f32x4 zero = {0.f, 0.f, 0.f, 0.f};
    f32x4 acc[8][4];
#pragma unroll
    for (int i = 0; i < 8; ++i)
#pragma unroll
        for (int j = 0; j < 4; ++j) acc[i][j] = zero;

    // ---- staging map: thread t -> (row t/8 within 64-row round, slot t%8) ----
    const int sRow = tid >> 3;                 // 0..63
    const int sSlot = (tid & 7) ^ (sRow & 7);  // inverse-swizzled global slot
    const bf16* gA = Abf + (size_t)(bm0 + sRow) * E_SZ + sSlot * 8;
    const bf16* gB = Pbf + (size_t)(bn0 + sRow) * E_SZ + sSlot * 8;
    const int ldsChunk = wave * 512;           // element base of this wave's 1KB chunk

    // ---- fragment read offsets (same XOR on the read side) ----
    int aOff[8], bOff[4], sl[2];
#pragma unroll
    for (int mi = 0; mi < 8; ++mi)
        aOff[mi] = (wm * 128 + mi * 16 + l16) * BK;
#pragma unroll
    for (int ni = 0; ni < 4; ++ni)
        bOff[ni] = (wn * 64 + ni * 16 + l16) * BK;
#pragma unroll
    for (int kh = 0; kh < 2; ++kh)
        sl[kh] = ((kh * 4 + quad) ^ (l16 & 7)) * 8;

    __syncthreads();   // full drain: vmcnt==0 for every wave entering the loop

    // prologue: stage K-tile 0 into buffer 0 (8 loads: 4 rounds A + 4 rounds B)
#pragma unroll
    for (int rnd = 0; rnd < 4; ++rnd)
        async16(gA + (size_t)rnd * 64 * E_SZ, &Alds[0][rnd * 4096 + ldsChunk]);
#pragma unroll
    for (int rnd = 0; rnd < 4; ++rnd)
        async16(gB + (size_t)rnd * 64 * E_SZ, &Blds[0][rnd * 4096 + ldsChunk]);

#pragma unroll
    for (int t = 0; t < 8; ++t) {
        const int cur = t & 1;
        // BARRIER_A: everyone finished reading buf[1-cur] (iteration t-1)
        __builtin_amdgcn_s_barrier();
        __builtin_amdgcn_sched_barrier(0);
        if (t < 7) {
            const int kOff = (t + 1) * BK;
#pragma unroll
            for (int rnd = 0; rnd < 4; ++rnd)
                async16(gA + (size_t)rnd * 64 * E_SZ + kOff,
                        &Alds[1 - cur][rnd * 4096 + ldsChunk]);
#pragma unroll
            for (int rnd = 0; rnd < 4; ++rnd)
                async16(gB + (size_t)rnd * 64 * E_SZ + kOff,
                        &Blds[1 - cur][rnd * 4096 + ldsChunk]);
            // my 8 tile-t loads done; 8 prefetch loads stay in flight
            asm volatile("s_waitcnt vmcnt(8)" ::: "memory");
        } else {
            asm volatile("s_waitcnt vmcnt(0)" ::: "memory");
        }
        // BARRIER_B: all waves' tile-t loads have landed in buf[cur]
        __builtin_amdgcn_s_barrier();
        __builtin_amdgcn_sched_barrier(0);

#pragma unroll
        for (int kh = 0; kh < 2; ++kh) {
            bf16x8 af[8], bf_[4];
#pragma unroll
            for (int mi = 0; mi < 8; ++mi)
                af[mi] = *(const bf16x8*)&Alds[cur][aOff[mi] + sl[kh]];
#pragma unroll
            for (int ni = 0; ni < 4; ++ni)
                bf_[ni] = *(const bf16x8*)&Blds[cur][bOff[ni] + sl[kh]];
#pragma unroll
            for (int mi = 0; mi < 8; ++mi)
#pragma unroll
                for (int ni = 0; ni < 4; ++ni)
                    acc[mi][ni] = __builtin_amdgcn_mfma_f32_16x16x32_bf16(
                        af[mi], bf_[ni], acc[mi][ni], 0, 0, 0);
        }
    }
    __builtin_amdgcn_sched_barrier(0);  // keep epilogue loads out of the K-loop

    // -------- epilogue: per-class (column) reductions --------
    int colG[4];
    float oS[4], iE[4];
#pragma unroll
    for (int ni = 0; ni < 4; ++ni) {
        colG[ni] = bn0 + wn * 64 + ni * 16 + l16;
        oS[ni] = oSimA[colG[ni]];
        iE[ni] = iEffA[colG[ni]];
    }
    float negE[4] = {0.f, 0.f, 0.f, 0.f};
    float negV[4] = {0.f, 0.f, 0.f, 0.f};
#pragma unroll
    for (int mi = 0; mi < 8; ++mi) {
#pragma unroll
        for (int r = 0; r < 4; ++r) {
            int rowL = wm * 128 + mi * 16 + quad * 4 + r;
            int tgt = tgtLds[rowL];
#pragma unroll
            for (int ni = 0; ni < 4; ++ni) {
                float cosv = acc[mi][ni][r];
                if (tgt == colG[ni]) {
                    // positive position (rare): also count the class here —
                    // each batch row hits exactly one (bx,by) block once.
                    atomicAdd(&posExp[colG[ni]],
                              __builtin_amdgcn_exp2f(A2LOG2E * (MRG - cosv)));
                    atomicAdd(&cCnt[colG[ni]], 1);
                } else {
                    float nv = (cosv < oS[ni]) ? iE[ni] : 1.0f;
                    negE[ni] += __builtin_amdgcn_exp2f(A2LOG2E * (cosv + MRG) * nv);
                    negV[ni] += nv;
                }
            }
        }
    }
    // quad-level register reduce: quad==0 lane holds the 128-row partial
#pragma unroll
    for (int ni = 0; ni < 4; ++ni) {
        negE[ni] += __shfl_xor(negE[ni], 16); negE[ni] += __shfl_xor(negE[ni], 32);
        negV[ni] += __shfl_xor(negV[ni], 16); negV[ni] += __shfl_xor(negV[ni], 32);
    }
    // combine the two wm-waves per column range in LDS, then one coalesced
    // global atomic per column.
    float* nEsh = scratch;          // 256 floats
    float* nVsh = scratch + BN;     // 256 floats
    scratch[tid] = 0.0f;            // 512 threads zero 512 floats
    __syncthreads();
    if (quad == 0) {
#pragma unroll
        for (int ni = 0; ni < 4; ++ni) {
            int cl = wn * 64 + ni * 16 + l16;
            atomicAdd(&nEsh[cl], negE[ni]);
            atomicAdd(&nVsh[cl], negV[ni]);
        }
    }
    __syncthreads();
    if (tid < BN) {
        atomicAdd(&negExp[bn0 + tid], nEsh[tid]);
        atomicAdd(&negVals[bn0 + tid], nVsh[tid]);
    }
}

// ---------------- finalize: 16 blocks, last-block-ticket completes ----------------
__global__ __launch_bounds__(256) void finalize(
    const float* __restrict__ posExp, const float* __restrict__ negExp,
    const float* __restrict__ negVals, const int* __restrict__ cCnt,
    float* __restrict__ acc4, int* __restrict__ counter,
    float* __restrict__ out) {
    const int tid = threadIdx.x;
    float pt = 0.f, nt = 0.f, pws = 0.f, nws = 0.f;
#pragma unroll
    for (int j = 0; j < 4; ++j) {
        int c = blockIdx.x * 1024 + j * 256 + tid;
        pt += log1pf(posExp[c]);
        nt += log1pf(negExp[c]);
        int cnt = cCnt[c];
        pws += (cnt > 0) ? 1.0f : 0.0f;
        int Nc = B_SZ - cnt;
        nws += (Nc > 0) ? negVals[c] / (float)Nc : 0.0f;
    }
#pragma unroll
    for (int m = 1; m < 64; m <<= 1) {
        pt += __shfl_xor(pt, m);
        nt += __shfl_xor(nt, m);
        pws += __shfl_xor(pws, m);
        nws += __shfl_xor(nws, m);
    }
    __shared__ float red[4][4];
    int wv = tid >> 6;
    if ((tid & 63) == 0) {
        red[wv][0] = pt; red[wv][1] = nt; red[wv][2] = pws; red[wv][3] = nws;
    }
    __syncthreads();
    if (tid < 4) {
        float s = red[0][tid] + red[1][tid] + red[2][tid] + red[3][tid];
        atomicAdd(&acc4[tid], s);
    }
    // make this block's contribution globally visible, then take a ticket
    __syncthreads();          // acc4 atomics drained (vmcnt) before ticket
    __threadfence();
    if (tid == 0) {
        int ticket = atomicAdd(counter, 1);
        if (ticket == 15) {   // last block: all 16 contributions are in
            float a0 = atomicAdd(&acc4[0], 0.0f);
            float a1 = atomicAdd(&acc4[1], 0.0f);
            float a2 = atomicAdd(&acc4[2], 0.0f);
            float a3 = atomicAdd(&acc4[3], 0.0f);
            out[0] = a0 / a2 + a1 / a3;
        }
    }
}

extern "C" void kernel_launch(void* const* d_in, const int* in_sizes, int n_in,
                              void* d_out, int out_size, void* d_ws, size_t ws_size,
                              hipStream_t stream) {
    const float* inputs = (const float*)d_in[0];
    const int* targets = (const int*)d_in[1];
    const float* proxies = (const float*)d_in[2];
    const float* effNum = (const float*)d_in[3];
    const float* lSim = (const float*)d_in[4];
    float* out = (float*)d_out;

    // workspace layout
    bf16* Pbf = (bf16*)d_ws;                        // C*E bf16  (16 MB)
    bf16* Abf = Pbf + (size_t)C_SZ * E_SZ;          // B*E bf16  (1 MB)
    float* oSim = (float*)(Abf + (size_t)B_SZ * E_SZ);
    float* iEff = oSim + C_SZ;
    float* posExp = iEff + C_SZ;                    // zeroBase starts here
    float* negExp = posExp + C_SZ;
    float* negVals = negExp + C_SZ;
    int* cCnt = (int*)(negVals + C_SZ);
    float* acc4 = (float*)(cCnt + C_SZ);
    int* counter = (int*)(acc4 + 4);
    // + 3 floats pad (zeroed) after counter

    prep_fused<<<4481, 256, 0, stream>>>(proxies, Pbf, inputs, Abf,
                                         effNum, lSim, oSim, iEff, posExp);
    gemm_epilogue<<<dim3(C_SZ / BN, B_SZ / BM), 512, 0, stream>>>(
        Abf, Pbf, targets, oSim, iEff, posExp, negExp, negVals, cCnt);
    finalize<<<16, 256, 0, stream>>>(posExp, negExp, negVals, cCnt,
                                     acc4, counter, out);
}